// Round 1
// baseline (322.763 us; speedup 1.0000x reference)
//
#include <hip/hip_runtime.h>
#include <stdint.h>

typedef __attribute__((ext_vector_type(8))) __bf16 bf16x8;
typedef __attribute__((ext_vector_type(4))) float f32x4;

#define N_LEAVES 524288

// fp32 -> bf16 round-to-nearest-even (bit manip; values are finite)
__device__ __forceinline__ uint16_t f2bf(float f) {
  uint32_t u = __float_as_uint(f);
  return (uint16_t)((u + 0x7fffu + ((u >> 16) & 1u)) >> 16);
}

// Swizzled LDS byte address for A-tile: row-major [64][256] bf16 (512 B/row),
// 16B chunks XORed by (row&7) to kill the 512B-stride bank conflict (T2).
__device__ __forceinline__ int lds_addr(int row, int chunk) {
  return row * 512 + ((chunk ^ (row & 7)) << 4);
}

// ---- shared MFMA compute + epilogue for one 64-row x 128-col tile ----
// A staged (swizzled) in Alds. B (Wc_w as bf16, row-major [128][256]) read to regs.
// Y written bf16 row-major [n][128].
__device__ __forceinline__ void mfma_tile(
    const uint8_t* Alds, const uint16_t* __restrict__ Wbf,
    const float* __restrict__ Wnon, const float* __restrict__ bias,
    const int* __restrict__ nidx, int lvl_off, int r0,
    uint16_t* __restrict__ Y)
{
  const int tid = threadIdx.x;
  const int w = tid >> 6, lane = tid & 63;
  const int Rw = (w >> 2) * 32;      // 2 wave-rows of 32
  const int Cw = (w & 3) * 32;       // 4 wave-cols of 32
  const int l15 = lane & 15, l4 = lane >> 4;

  // B fragments: lane holds col (Cw+cf*16+l15), k = l4*8 + s*32 + i
  bf16x8 b[2][8];
#pragma unroll
  for (int cf = 0; cf < 2; ++cf) {
    const uint16_t* bp = Wbf + (Cw + cf * 16 + l15) * 256 + l4 * 8;
#pragma unroll
    for (int s = 0; s < 8; ++s)
      b[cf][s] = *reinterpret_cast<const bf16x8*>(bp + s * 32);
  }

  f32x4 acc[2][2] = {};
  __syncthreads();

#pragma unroll
  for (int s = 0; s < 8; ++s) {
    bf16x8 a0 = *reinterpret_cast<const bf16x8*>(&Alds[lds_addr(Rw + l15,      s * 4 + l4)]);
    bf16x8 a1 = *reinterpret_cast<const bf16x8*>(&Alds[lds_addr(Rw + 16 + l15, s * 4 + l4)]);
    acc[0][0] = __builtin_amdgcn_mfma_f32_16x16x32_bf16(a0, b[0][s], acc[0][0], 0, 0, 0);
    acc[0][1] = __builtin_amdgcn_mfma_f32_16x16x32_bf16(a0, b[1][s], acc[0][1], 0, 0, 0);
    acc[1][0] = __builtin_amdgcn_mfma_f32_16x16x32_bf16(a1, b[0][s], acc[1][0], 0, 0, 0);
    acc[1][1] = __builtin_amdgcn_mfma_f32_16x16x32_bf16(a1, b[1][s], acc[1][1], 0, 0, 0);
  }

  // epilogue: D row = Rw + rf*16 + l4*4 + reg ; col = Cw + cf*16 + l15
#pragma unroll
  for (int rf = 0; rf < 2; ++rf) {
#pragma unroll
    for (int reg = 0; reg < 4; ++reg) {
      int grow = r0 + Rw + rf * 16 + l4 * 4 + reg;
      int ni = nidx[lvl_off + grow];
#pragma unroll
      for (int cf = 0; cf < 2; ++cf) {
        int col = Cw + cf * 16 + l15;
        float v = acc[rf][cf][reg] + bias[col] + Wnon[ni * 128 + col];
        Y[(size_t)grow * 128 + col] = f2bf(tanhf(v));
      }
    }
  }
}

// ---- generic level: X = prev states viewed (n,256) bf16 ----
__global__ __launch_bounds__(512, 4)
void level_kernel(const uint16_t* __restrict__ X, uint16_t* __restrict__ Y,
                  const uint16_t* __restrict__ Wbf, const float* __restrict__ Wnon,
                  const float* __restrict__ bias, const int* __restrict__ nidx,
                  int lvl_off)
{
  __shared__ uint8_t Alds[32768];
  const int tid = threadIdx.x;
  const int r0 = blockIdx.x * 64;
  const uint8_t* Xb = reinterpret_cast<const uint8_t*>(X) + (size_t)r0 * 512;
#pragma unroll
  for (int i = 0; i < 4; ++i) {
    int d = i * 512 + tid;                 // 16B chunk index, 2048 total
    int4 v = *reinterpret_cast<const int4*>(Xb + d * 16);
    *reinterpret_cast<int4*>(&Alds[lds_addr(d >> 5, d & 31)]) = v;
  }
  mfma_tile(Alds, Wbf, Wnon, bias, nidx, lvl_off, r0, Y);
}

// ---- leaf level: gather embeddings, convert, stage ----
__global__ __launch_bounds__(512, 4)
void leaf_kernel(const int* __restrict__ pos_idx, const int* __restrict__ wrd_idx,
                 const float* __restrict__ Wpos, const float* __restrict__ Wwrd,
                 uint16_t* __restrict__ Y, const uint16_t* __restrict__ Wbf,
                 const float* __restrict__ Wnon, const float* __restrict__ bias,
                 const int* __restrict__ nidx)
{
  __shared__ uint8_t Alds[32768];
  const int tid = threadIdx.x;
  const int r0 = blockIdx.x * 64;
  {
    int ll = tid >> 2;                     // local leaf 0..127
    int sub = tid & 3;                     // 32-float column group
    int leaf = r0 * 2 + ll;
    int c0 = sub * 32;
    const float* src = (c0 < 64) ? (Wpos + (size_t)pos_idx[leaf] * 64 + c0)
                                 : (Wwrd + (size_t)wrd_idx[leaf] * 64 + (c0 - 64));
    int arow = ll >> 1;
    int cbase = (ll & 1) * 16 + sub * 4;   // 16B-chunk index base within A row
#pragma unroll
    for (int ch = 0; ch < 4; ++ch) {
      float4 f0 = reinterpret_cast<const float4*>(src)[ch * 2];
      float4 f1 = reinterpret_cast<const float4*>(src)[ch * 2 + 1];
      union { int4 v; uint16_t u[8]; } pk;
      pk.u[0] = f2bf(f0.x); pk.u[1] = f2bf(f0.y); pk.u[2] = f2bf(f0.z); pk.u[3] = f2bf(f0.w);
      pk.u[4] = f2bf(f1.x); pk.u[5] = f2bf(f1.y); pk.u[6] = f2bf(f1.z); pk.u[7] = f2bf(f1.w);
      *reinterpret_cast<int4*>(&Alds[lds_addr(arow, cbase + ch)]) = pk.v;
    }
  }
  mfma_tile(Alds, Wbf, Wnon, bias, nidx, /*lvl_off=*/0, r0, Y);
}

// ---- tail: levels n=64..1 in ONE block, states ping-pong in LDS ----
__global__ __launch_bounds__(512, 4)
void tail_kernel(const uint16_t* __restrict__ X, const uint16_t* __restrict__ Wbf,
                 const float* __restrict__ Wnon, const float* __restrict__ bias,
                 const int* __restrict__ nidx, int base_off, float* __restrict__ out)
{
  __shared__ uint8_t P[2][32768];
  const int tid = threadIdx.x;
  // stage n=64 level input (128 prev rows = 64 A-rows x 512B = 32KB)
#pragma unroll
  for (int i = 0; i < 4; ++i) {
    int d = i * 512 + tid;
    int4 v = *reinterpret_cast<const int4*>(reinterpret_cast<const uint8_t*>(X) + d * 16);
    *reinterpret_cast<int4*>(&P[0][lds_addr(d >> 5, d & 31)]) = v;
  }
  const int w = tid >> 6, lane = tid & 63;
  const int Rw = (w >> 2) * 32, Cw = (w & 3) * 32;
  const int l15 = lane & 15, l4 = lane >> 4;
  bf16x8 b[2][8];
#pragma unroll
  for (int cf = 0; cf < 2; ++cf) {
    const uint16_t* bp = Wbf + (Cw + cf * 16 + l15) * 256 + l4 * 8;
#pragma unroll
    for (int s = 0; s < 8; ++s)
      b[cf][s] = *reinterpret_cast<const bf16x8*>(bp + s * 32);
  }
  __syncthreads();

  int off = base_off;
  int cur = 0;
  for (int n = 64; n >= 1; n >>= 1) {
    f32x4 acc[2][2] = {};
#pragma unroll
    for (int s = 0; s < 8; ++s) {
      bf16x8 a0 = *reinterpret_cast<const bf16x8*>(&P[cur][lds_addr(Rw + l15,      s * 4 + l4)]);
      bf16x8 a1 = *reinterpret_cast<const bf16x8*>(&P[cur][lds_addr(Rw + 16 + l15, s * 4 + l4)]);
      acc[0][0] = __builtin_amdgcn_mfma_f32_16x16x32_bf16(a0, b[0][s], acc[0][0], 0, 0, 0);
      acc[0][1] = __builtin_amdgcn_mfma_f32_16x16x32_bf16(a0, b[1][s], acc[0][1], 0, 0, 0);
      acc[1][0] = __builtin_amdgcn_mfma_f32_16x16x32_bf16(a1, b[0][s], acc[1][0], 0, 0, 0);
      acc[1][1] = __builtin_amdgcn_mfma_f32_16x16x32_bf16(a1, b[1][s], acc[1][1], 0, 0, 0);
    }
#pragma unroll
    for (int rf = 0; rf < 2; ++rf) {
#pragma unroll
      for (int reg = 0; reg < 4; ++reg) {
        int rl = Rw + rf * 16 + l4 * 4 + reg;
        int rcl = rl < (n - 1) ? rl : (n - 1);   // clamp idx read (garbage rows)
        int ni = nidx[off + rcl];
#pragma unroll
        for (int cf = 0; cf < 2; ++cf) {
          int col = Cw + cf * 16 + l15;
          float v = acc[rf][cf][reg] + bias[col] + Wnon[ni * 128 + col];
          float y = tanhf(v);
          if (n == 1) {
            if (rl == 0) out[col] = y;           // final output fp32
          } else {
            // write Y row rl into next level's A layout: row rl>>1, colA=(rl&1)*128+col
            int r2 = rl >> 1;
            int colA = (rl & 1) * 128 + col;
            int addr = r2 * 512 + ((((colA >> 3) ^ (r2 & 7))) << 4) + (colA & 7) * 2;
            *reinterpret_cast<uint16_t*>(&P[cur ^ 1][addr]) = f2bf(y);
          }
        }
      }
    }
    off += n;
    cur ^= 1;
    __syncthreads();
  }
}

// ---- prep: Wc_w fp32 [128][256] -> bf16 (same layout) ----
__global__ void prep_w(const float* __restrict__ W, uint16_t* __restrict__ Wbf) {
  int i = blockIdx.x * 256 + threadIdx.x;   // 32768 elems
  Wbf[i] = f2bf(W[i]);
}

extern "C" void kernel_launch(void* const* d_in, const int* in_sizes, int n_in,
                              void* d_out, int out_size, void* d_ws, size_t ws_size,
                              hipStream_t stream)
{
  const int*   pos_idx = (const int*)d_in[0];
  const int*   wrd_idx = (const int*)d_in[1];
  const int*   non_idx = (const int*)d_in[2];
  const float* Wwrd    = (const float*)d_in[3];
  const float* Wpos    = (const float*)d_in[4];
  const float* Wnon    = (const float*)d_in[5];
  const float* Wc_w    = (const float*)d_in[6];
  const float* Wc_b    = (const float*)d_in[7];
  float* out = (float*)d_out;

  uint8_t* ws = (uint8_t*)d_ws;
  uint16_t* Wbf = (uint16_t*)ws;                                  // 64 KiB
  uint16_t* S1  = (uint16_t*)(ws + 65536);                        // 64 MiB (262144x128 bf16)
  uint16_t* S2  = (uint16_t*)(ws + 65536 + 67108864);             // 32 MiB (131072x128 bf16)

  prep_w<<<128, 256, 0, stream>>>(Wc_w, Wbf);

  // level n=262144 (leaf-fused): out -> S1
  leaf_kernel<<<4096, 512, 0, stream>>>(pos_idx, wrd_idx, Wpos, Wwrd,
                                        S1, Wbf, Wnon, Wc_b, non_idx);
  int off = 262144;
  uint16_t* bufs[2] = {S1, S2};
  int curb = 0;
  for (int n = 131072; n >= 128; n >>= 1) {
    level_kernel<<<n / 64, 512, 0, stream>>>(bufs[curb], bufs[curb ^ 1],
                                             Wbf, Wnon, Wc_b, non_idx, off);
    off += n;
    curb ^= 1;
  }
  // tail: levels 64..1 in one block; reads n=128 output (in bufs[curb])
  tail_kernel<<<1, 512, 0, stream>>>(bufs[curb], Wbf, Wnon, Wc_b, non_idx, off, out);
}